// Round 1
// baseline (973.818 us; speedup 1.0000x reference)
//
#include <hip/hip_runtime.h>
#include <hip/hip_bf16.h>

// SAGE layer, restructured via linearity of the message Linear:
//   msum[n] = W_msg · (Σ_{e->n} [nf[src] ‖ ef[e]])  ; bias folded post-mean.
// Phase 1: scatter-add 128-dim edge inputs into ssum[n][128] + cnt[n] (f32 atomics).
// Phase 2: per-16-node tile, bf16 MFMA: GEMM1 (ssum->h_neigh) fused with
//          GEMM2 (apply) + bias + relu.

typedef __attribute__((ext_vector_type(8))) short bf16x8;
typedef __attribute__((ext_vector_type(4))) float f32x4;

__device__ __forceinline__ short f2bf(float f) {
  union { float f; unsigned u; } v; v.f = f;
  unsigned u = v.u;
  u += 0x7fffu + ((u >> 16) & 1u);   // round-to-nearest-even
  return (short)(u >> 16);
}

__device__ __forceinline__ bf16x8 pack8(float4 a, float4 b) {
  bf16x8 r;
  r[0] = f2bf(a.x); r[1] = f2bf(a.y); r[2] = f2bf(a.z); r[3] = f2bf(a.w);
  r[4] = f2bf(b.x); r[5] = f2bf(b.y); r[6] = f2bf(b.z); r[7] = f2bf(b.w);
  return r;
}

// ---------------- Phase 1: edge scatter ----------------
// wave per edge: lane l adds nf[src][l] to ssum[dst][l] and ef[e][l] to
// ssum[dst][64+l]; lane 0 bumps cnt[dst].
__global__ __launch_bounds__(256) void edge_scatter(
    const float* __restrict__ nfeats, const float* __restrict__ efeats,
    const int* __restrict__ src, const int* __restrict__ dst,
    float* __restrict__ ssum, float* __restrict__ cnt, int E)
{
  const int lane = threadIdx.x & 63;
  const int wave = (blockIdx.x * blockDim.x + threadIdx.x) >> 6;
  const int nw = (gridDim.x * blockDim.x) >> 6;
  for (int e = wave; e < E; e += nw) {
    const int s = src[e];
    const int d = dst[e];
    const float nf = nfeats[(size_t)s * 64 + lane];
    const float ef = efeats[(size_t)e * 64 + lane];
    float* b = ssum + (size_t)d * 128;
    atomicAdd(b + lane, nf);
    atomicAdd(b + 64 + lane, ef);
    if (lane == 0) atomicAdd(cnt + d, 1.0f);
  }
}

// ---------------- Phase 2: fused node GEMMs ----------------
// One wave handles 16 nodes. mfma_f32_16x16x32_bf16 fragment maps (verified
// gfx950): A[i][k]: lane=(k/8)*16+i, elem=k%8 ; B[k][j]: lane=(k/8)*16+j,
// elem=k%8 ; D[i][j]: lane=(i/4)*16+j, reg=i%4.
__global__ __launch_bounds__(256) void node_apply(
    const float* __restrict__ nfeats, const float* __restrict__ ssum,
    const float* __restrict__ cnt,
    const float* __restrict__ W_msg, const float* __restrict__ b_msg,
    const float* __restrict__ W_apply, const float* __restrict__ b_apply,
    float* __restrict__ out, int ntiles)
{
  __shared__ float hn[4][16 * 68];            // per-wave h_neigh scratch, padded
  const int wid = threadIdx.x >> 6;
  const int lane = threadIdx.x & 63;
  const int r = lane & 15;                    // A-row / B-col / D-col index
  const int g = lane >> 4;                    // 0..3
  const int tile = blockIdx.x * 4 + wid;
  if (tile >= ntiles) return;

  // Preload W fragments as B operands: B[k][j] = W[j][k]
  bf16x8 wm[4][4], wa[4][4];
#pragma unroll
  for (int kc = 0; kc < 4; ++kc) {
#pragma unroll
    for (int nc = 0; nc < 4; ++nc) {
      const float* p = W_msg + (nc * 16 + r) * 128 + kc * 32 + g * 8;
      wm[kc][nc] = pack8(*(const float4*)p, *(const float4*)(p + 4));
      const float* q = W_apply + (nc * 16 + r) * 128 + kc * 32 + g * 8;
      wa[kc][nc] = pack8(*(const float4*)q, *(const float4*)(q + 4));
    }
  }

  const int n0 = tile * 16;

  // GEMM1: msum_tile = ssum_tile(16x128) @ W_msg^T(128x64)
  f32x4 acc[4] = {};
#pragma unroll
  for (int kc = 0; kc < 4; ++kc) {
    const float* p = ssum + (size_t)(n0 + r) * 128 + kc * 32 + g * 8;
    const bf16x8 af = pack8(*(const float4*)p, *(const float4*)(p + 4));
#pragma unroll
    for (int nc = 0; nc < 4; ++nc)
      acc[nc] = __builtin_amdgcn_mfma_f32_16x16x32_bf16(af, wm[kc][nc], acc[nc], 0, 0, 0);
  }

  // h_neigh = cnt>0 ? msum/cnt + b_msg : 0   -> LDS (same-wave, no barrier)
  float cn[4];
#pragma unroll
  for (int q = 0; q < 4; ++q) cn[q] = cnt[n0 + g * 4 + q];
#pragma unroll
  for (int nc = 0; nc < 4; ++nc) {
    const float bm = b_msg[nc * 16 + r];
#pragma unroll
    for (int q = 0; q < 4; ++q) {
      const float v = cn[q] > 0.f ? acc[nc][q] / cn[q] + bm : 0.f;
      hn[wid][(g * 4 + q) * 68 + nc * 16 + r] = v;
    }
  }

  // GEMM2: out_tile = [nfeats_tile ‖ h_neigh_tile](16x128) @ W_apply^T
  f32x4 acc2[4] = {};
#pragma unroll
  for (int kc = 0; kc < 2; ++kc) {
    const float* p = nfeats + (size_t)(n0 + r) * 64 + kc * 32 + g * 8;
    const bf16x8 af = pack8(*(const float4*)p, *(const float4*)(p + 4));
#pragma unroll
    for (int nc = 0; nc < 4; ++nc)
      acc2[nc] = __builtin_amdgcn_mfma_f32_16x16x32_bf16(af, wa[kc][nc], acc2[nc], 0, 0, 0);
  }
#pragma unroll
  for (int kc = 2; kc < 4; ++kc) {
    const float* p = &hn[wid][r * 68 + (kc - 2) * 32 + g * 8];
    const bf16x8 af = pack8(*(const float4*)p, *(const float4*)(p + 4));
#pragma unroll
    for (int nc = 0; nc < 4; ++nc)
      acc2[nc] = __builtin_amdgcn_mfma_f32_16x16x32_bf16(af, wa[kc][nc], acc2[nc], 0, 0, 0);
  }

  // bias + relu + store
#pragma unroll
  for (int nc = 0; nc < 4; ++nc) {
    const float ba = b_apply[nc * 16 + r];
#pragma unroll
    for (int q = 0; q < 4; ++q) {
      float v = acc2[nc][q] + ba;
      v = v > 0.f ? v : 0.f;
      out[(size_t)(n0 + g * 4 + q) * 64 + nc * 16 + r] = v;
    }
  }
}

extern "C" void kernel_launch(void* const* d_in, const int* in_sizes, int n_in,
                              void* d_out, int out_size, void* d_ws, size_t ws_size,
                              hipStream_t stream) {
  const float* nfeats  = (const float*)d_in[0];
  const float* efeats  = (const float*)d_in[1];
  const int*   src     = (const int*)d_in[2];
  const int*   dst     = (const int*)d_in[3];
  const float* W_msg   = (const float*)d_in[4];
  const float* b_msg   = (const float*)d_in[5];
  const float* W_apply = (const float*)d_in[6];
  const float* b_apply = (const float*)d_in[7];
  float* out = (float*)d_out;

  const int N = in_sizes[0] / 64;
  const int E = in_sizes[2];

  float* cnt  = (float*)d_ws;           // N floats
  float* ssum = cnt + N;                // N*128 floats (N*4 % 16 == 0 here)
  const size_t zero_bytes = (size_t)N * 4 + (size_t)N * 128 * 4;
  hipMemsetAsync(d_ws, 0, zero_bytes, stream);

  edge_scatter<<<2048, 256, 0, stream>>>(nfeats, efeats, src, dst, ssum, cnt, E);

  const int ntiles = (N + 15) / 16;     // N=100000 -> 6250, exact
  const int nblocks = (ntiles + 3) / 4;
  node_apply<<<nblocks, 256, 0, stream>>>(nfeats, ssum, cnt, W_msg, b_msg,
                                          W_apply, b_apply, out, ntiles);
}

// Round 2
// 694.913 us; speedup vs baseline: 1.4014x; 1.4014x over previous
//
#include <hip/hip_runtime.h>
#include <hip/hip_bf16.h>

// SAGE layer via linearity of the message Linear:
//   msum[n] = W_msg · (Σ_{e->n} [nf[src] ‖ ef[e]]) ; bias folded post-mean.
// CSR build (hist + scan + bin) -> per-node gather-reduce (NO f32 atomics)
// -> fused MFMA node kernel. ssum stored bf16 (write-once), weights pre-packed.

typedef __attribute__((ext_vector_type(8))) short bf16x8;
typedef __attribute__((ext_vector_type(4))) float f32x4;

__device__ __forceinline__ short f2bf(float f) {
  union { float f; unsigned u; } v; v.f = f;
  unsigned u = v.u;
  u += 0x7fffu + ((u >> 16) & 1u);   // round-to-nearest-even
  return (short)(u >> 16);
}

__device__ __forceinline__ bf16x8 pack8(float4 a, float4 b) {
  bf16x8 r;
  r[0] = f2bf(a.x); r[1] = f2bf(a.y); r[2] = f2bf(a.z); r[3] = f2bf(a.w);
  r[4] = f2bf(b.x); r[5] = f2bf(b.y); r[6] = f2bf(b.z); r[7] = f2bf(b.w);
  return r;
}

// ---- prep: nfeats f32->bf16, and pack W_msg/W_apply into MFMA B-fragments ----
__global__ __launch_bounds__(256) void prep_k(
    const float* __restrict__ nf, const float* __restrict__ Wm,
    const float* __restrict__ Wa, short* __restrict__ nf16,
    short* __restrict__ wpack, int conv_blocks, long total_nf)
{
  if ((int)blockIdx.x < conv_blocks) {
    long t = (long)blockIdx.x * 256 + threadIdx.x;
    long b8 = t * 8;
    if (b8 + 8 <= total_nf) {
      const float* p = nf + b8;
      *(bf16x8*)(nf16 + b8) = pack8(*(const float4*)p, *(const float4*)(p + 4));
    }
  } else {
    // 2048 fragment-lanes: id -> (w, kc, nc, lane); 8 per thread
    int t = threadIdx.x;
#pragma unroll
    for (int j = 0; j < 8; ++j) {
      int id = t * 8 + j;
      int w = id >> 10, kc = (id >> 8) & 3, nc = (id >> 6) & 3, lane = id & 63;
      int r = lane & 15, g = lane >> 4;
      const float* W = w ? Wa : Wm;
      const float* p = W + (nc * 16 + r) * 128 + kc * 32 + g * 8;
      *(bf16x8*)(wpack + (long)id * 8) = pack8(*(const float4*)p, *(const float4*)(p + 4));
    }
  }
}

// ---- CSR build ----
__global__ __launch_bounds__(256) void hist_k(const int* __restrict__ dst,
                                              int* __restrict__ hist, int E) {
  int i = blockIdx.x * blockDim.x + threadIdx.x;
  int stride = gridDim.x * blockDim.x;
  for (; i < E; i += stride) atomicAdd(&hist[dst[i]], 1);
}

__global__ __launch_bounds__(256) void scan1_k(const int* __restrict__ hist,
                                               int* __restrict__ off,
                                               int* __restrict__ parts, int N) {
  __shared__ int sh[256];
  int tid = threadIdx.x;
  int base = blockIdx.x * 1024 + tid * 4;
  int v[4], ts = 0;
#pragma unroll
  for (int j = 0; j < 4; ++j) {
    int idx = base + j;
    v[j] = (idx < N) ? hist[idx] : 0;
    ts += v[j];
  }
  sh[tid] = ts;
  __syncthreads();
  for (int o = 1; o < 256; o <<= 1) {
    int y = (tid >= o) ? sh[tid - o] : 0;
    __syncthreads();
    sh[tid] += y;
    __syncthreads();
  }
  int run = sh[tid] - ts;   // exclusive prefix for this thread
#pragma unroll
  for (int j = 0; j < 4; ++j) {
    int idx = base + j;
    if (idx < N) off[idx] = run;
    run += v[j];
  }
  if (tid == 255) parts[blockIdx.x] = sh[255];
}

__global__ void scan2_k(int* __restrict__ parts, int* __restrict__ off,
                        int nparts, int N, int E) {
  int lane = threadIdx.x & 63;
  int i0 = 2 * lane, i1 = 2 * lane + 1;
  int p0 = (i0 < nparts) ? parts[i0] : 0;
  int p1 = (i1 < nparts) ? parts[i1] : 0;
  int s = p0 + p1;
  int x = s;
  for (int o = 1; o < 64; o <<= 1) {
    int y = __shfl_up(x, o);
    if (lane >= o) x += y;
  }
  int ex = x - s;   // exclusive prefix of pair-sums
  if (i0 < nparts) parts[i0] = ex;
  if (i1 < nparts) parts[i1] = ex + p0;
  if (lane == 0) off[N] = E;
}

__global__ __launch_bounds__(256) void scan3_k(int* __restrict__ off,
                                               int* __restrict__ woff,
                                               const int* __restrict__ parts, int N) {
  int p = parts[blockIdx.x];
  int base = blockIdx.x * 1024 + threadIdx.x;
#pragma unroll
  for (int j = 0; j < 4; ++j) {
    int idx = base + j * 256;
    if (idx < N) {
      int v = off[idx] + p;
      off[idx] = v;
      woff[idx] = v;
    }
  }
}

__global__ __launch_bounds__(256) void bin_k(
    const int* __restrict__ src, const int* __restrict__ dst,
    int* __restrict__ woff, int* __restrict__ seid, int* __restrict__ ssrc, int E) {
  int i = blockIdx.x * blockDim.x + threadIdx.x;
  int stride = gridDim.x * blockDim.x;
  for (; i < E; i += stride) {
    int d = dst[i];
    int pos = atomicAdd(&woff[d], 1);
    seid[pos] = i;
    ssrc[pos] = src[i];
  }
}

// ---- gather-reduce: one wave per node, lane = dim; write bf16 once ----
__global__ __launch_bounds__(256) void reduce_k(
    const float* __restrict__ nf, const float* __restrict__ ef,
    const int* __restrict__ off, const int* __restrict__ seid,
    const int* __restrict__ ssrc, short* __restrict__ ssum16, int N)
{
  int wave = (blockIdx.x * blockDim.x + threadIdx.x) >> 6;
  int lane = threadIdx.x & 63;
  if (wave >= N) return;
  int beg = off[wave], end = off[wave + 1];
  float anf = 0.f, aef = 0.f;
  int i = beg;
  for (; i + 1 < end; i += 2) {
    int s0 = ssrc[i], s1 = ssrc[i + 1];
    int e0 = seid[i], e1 = seid[i + 1];
    float x0 = nf[(size_t)s0 * 64 + lane];
    float x1 = nf[(size_t)s1 * 64 + lane];
    float y0 = ef[(size_t)e0 * 64 + lane];
    float y1 = ef[(size_t)e1 * 64 + lane];
    anf += x0 + x1;
    aef += y0 + y1;
  }
  if (i < end) {
    anf += nf[(size_t)ssrc[i] * 64 + lane];
    aef += ef[(size_t)seid[i] * 64 + lane];
  }
  short* row = ssum16 + (size_t)wave * 128;
  row[lane] = f2bf(anf);
  row[64 + lane] = f2bf(aef);
}

// ---- fused node GEMMs (bf16 inputs, pre-packed weights) ----
// mfma_f32_16x16x32_bf16 maps: A[i][k]: lane=(k/8)*16+i, elem=k%8 ;
// B[k][j]: lane=(k/8)*16+j, elem=k%8 ; D[i][j]: lane=(i/4)*16+j, reg=i%4.
__global__ __launch_bounds__(256) void node_apply(
    const short* __restrict__ nf16, const short* __restrict__ ssum16,
    const int* __restrict__ off, const short* __restrict__ wpack,
    const float* __restrict__ b_msg, const float* __restrict__ b_apply,
    float* __restrict__ out, int ntiles)
{
  __shared__ float hn[4][16 * 68];
  const int wid = threadIdx.x >> 6;
  const int lane = threadIdx.x & 63;
  const int r = lane & 15;
  const int g = lane >> 4;
  const int tile = blockIdx.x * 4 + wid;
  if (tile >= ntiles) return;
  const int n0 = tile * 16;

  bf16x8 wm[4][4], wa[4][4];
#pragma unroll
  for (int kc = 0; kc < 4; ++kc)
#pragma unroll
    for (int nc = 0; nc < 4; ++nc) {
      wm[kc][nc] = *(const bf16x8*)(wpack + ((long)((0 * 4 + kc) * 4 + nc) * 64 + lane) * 8);
      wa[kc][nc] = *(const bf16x8*)(wpack + ((long)((1 * 4 + kc) * 4 + nc) * 64 + lane) * 8);
    }

  // GEMM1: msum = ssum(16x128) @ W_msg^T
  f32x4 acc[4] = {};
#pragma unroll
  for (int kc = 0; kc < 4; ++kc) {
    const bf16x8 af = *(const bf16x8*)(ssum16 + (size_t)(n0 + r) * 128 + kc * 32 + g * 8);
#pragma unroll
    for (int nc = 0; nc < 4; ++nc)
      acc[nc] = __builtin_amdgcn_mfma_f32_16x16x32_bf16(af, wm[kc][nc], acc[nc], 0, 0, 0);
  }

  // h_neigh = cnt>0 ? msum/cnt + b_msg : 0  -> LDS (same wave, no barrier)
  float cn[4];
#pragma unroll
  for (int q = 0; q < 4; ++q) {
    int n = n0 + g * 4 + q;
    cn[q] = (float)(off[n + 1] - off[n]);
  }
#pragma unroll
  for (int nc = 0; nc < 4; ++nc) {
    const float bm = b_msg[nc * 16 + r];
#pragma unroll
    for (int q = 0; q < 4; ++q) {
      const float v = cn[q] > 0.f ? acc[nc][q] / cn[q] + bm : 0.f;
      hn[wid][(g * 4 + q) * 68 + nc * 16 + r] = v;
    }
  }

  // GEMM2: out = [nfeats ‖ h_neigh](16x128) @ W_apply^T
  f32x4 acc2[4] = {};
#pragma unroll
  for (int kc = 0; kc < 2; ++kc) {
    const bf16x8 af = *(const bf16x8*)(nf16 + (size_t)(n0 + r) * 64 + kc * 32 + g * 8);
#pragma unroll
    for (int nc = 0; nc < 4; ++nc)
      acc2[nc] = __builtin_amdgcn_mfma_f32_16x16x32_bf16(af, wa[kc][nc], acc2[nc], 0, 0, 0);
  }
#pragma unroll
  for (int kc = 2; kc < 4; ++kc) {
    const float* p = &hn[wid][r * 68 + (kc - 2) * 32 + g * 8];
    const bf16x8 af = pack8(*(const float4*)p, *(const float4*)(p + 4));
#pragma unroll
    for (int nc = 0; nc < 4; ++nc)
      acc2[nc] = __builtin_amdgcn_mfma_f32_16x16x32_bf16(af, wa[kc][nc], acc2[nc], 0, 0, 0);
  }

#pragma unroll
  for (int nc = 0; nc < 4; ++nc) {
    const float ba = b_apply[nc * 16 + r];
#pragma unroll
    for (int q = 0; q < 4; ++q) {
      float v = acc2[nc][q] + ba;
      v = v > 0.f ? v : 0.f;
      out[(size_t)(n0 + g * 4 + q) * 64 + nc * 16 + r] = v;
    }
  }
}

extern "C" void kernel_launch(void* const* d_in, const int* in_sizes, int n_in,
                              void* d_out, int out_size, void* d_ws, size_t ws_size,
                              hipStream_t stream) {
  const float* nfeats  = (const float*)d_in[0];
  const float* efeats  = (const float*)d_in[1];
  const int*   src     = (const int*)d_in[2];
  const int*   dst     = (const int*)d_in[3];
  const float* W_msg   = (const float*)d_in[4];
  const float* b_msg   = (const float*)d_in[5];
  const float* W_apply = (const float*)d_in[6];
  const float* b_apply = (const float*)d_in[7];
  float* out = (float*)d_out;

  const int N = in_sizes[0] / 64;
  const int E = in_sizes[2];
  const int nparts = (N + 1023) / 1024;

  auto alignup = [](size_t x) { return (x + 127) & ~(size_t)127; };
  char* ws = (char*)d_ws;
  size_t o = 0;
  int* hist   = (int*)(ws + o); o = alignup(o + (size_t)N * 4);
  int* off    = (int*)(ws + o); o = alignup(o + (size_t)(N + 1) * 4);
  int* woff   = (int*)(ws + o); o = alignup(o + (size_t)N * 4);
  int* parts  = (int*)(ws + o); o = alignup(o + (size_t)nparts * 4);
  int* seid   = (int*)(ws + o); o = alignup(o + (size_t)E * 4);
  int* ssrc   = (int*)(ws + o); o = alignup(o + (size_t)E * 4);
  short* ssum16 = (short*)(ws + o); o = alignup(o + (size_t)N * 128 * 2);
  short* nf16   = (short*)(ws + o); o = alignup(o + (size_t)N * 64 * 2);
  short* wpack  = (short*)(ws + o); o = alignup(o + (size_t)2048 * 8 * 2);

  hipMemsetAsync(hist, 0, (size_t)N * 4, stream);

  const long total_nf = (long)N * 64;
  const int conv_blocks = (int)((total_nf / 8 + 255) / 256);
  prep_k<<<conv_blocks + 1, 256, 0, stream>>>(nfeats, W_msg, W_apply, nf16, wpack,
                                              conv_blocks, total_nf);
  hist_k<<<1024, 256, 0, stream>>>(dst, hist, E);
  scan1_k<<<nparts, 256, 0, stream>>>(hist, off, parts, N);
  scan2_k<<<1, 64, 0, stream>>>(parts, off, nparts, N, E);
  scan3_k<<<nparts, 256, 0, stream>>>(off, woff, parts, N);
  bin_k<<<1024, 256, 0, stream>>>(src, dst, woff, seid, ssrc, E);
  reduce_k<<<(N + 3) / 4, 256, 0, stream>>>(nfeats, efeats, off, seid, ssrc, ssum16, N);

  const int ntiles = (N + 15) / 16;
  node_apply<<<(ntiles + 3) / 4, 256, 0, stream>>>(nf16, ssum16, off, wpack,
                                                   b_msg, b_apply, out, ntiles);
}

// Round 3
// 647.128 us; speedup vs baseline: 1.5048x; 1.0738x over previous
//
#include <hip/hip_runtime.h>
#include <hip/hip_bf16.h>

// SAGE layer via linearity of the message Linear:
//   msum[n] = W_msg · (Σ_{e->n} [nf[src] ‖ ef[e]]) ; bias folded post-mean.
// CSR build (hist + scan + bin(int2)) -> per-node float4 gather-reduce
// (4 edges/wave-iter, shfl_xor combine) -> fused MFMA node kernel.
// ssum stored bf16 write-once; weights pre-packed into MFMA fragments.

typedef __attribute__((ext_vector_type(8))) short bf16x8;
typedef __attribute__((ext_vector_type(4))) short bf16x4;
typedef __attribute__((ext_vector_type(4))) float f32x4;

__device__ __forceinline__ short f2bf(float f) {
  union { float f; unsigned u; } v; v.f = f;
  unsigned u = v.u;
  u += 0x7fffu + ((u >> 16) & 1u);   // round-to-nearest-even
  return (short)(u >> 16);
}

__device__ __forceinline__ bf16x8 pack8(float4 a, float4 b) {
  bf16x8 r;
  r[0] = f2bf(a.x); r[1] = f2bf(a.y); r[2] = f2bf(a.z); r[3] = f2bf(a.w);
  r[4] = f2bf(b.x); r[5] = f2bf(b.y); r[6] = f2bf(b.z); r[7] = f2bf(b.w);
  return r;
}

__device__ __forceinline__ bf16x4 pack4(float4 a) {
  bf16x4 r;
  r[0] = f2bf(a.x); r[1] = f2bf(a.y); r[2] = f2bf(a.z); r[3] = f2bf(a.w);
  return r;
}

// ---- prep (nf f32->bf16, W fragment pack) + dst histogram, one launch ----
__global__ __launch_bounds__(256) void prep_hist_k(
    const float* __restrict__ nf, const float* __restrict__ Wm,
    const float* __restrict__ Wa, short* __restrict__ nf16,
    short* __restrict__ wpack, const int* __restrict__ dst,
    int* __restrict__ hist, int conv_blocks, long total_nf, int E, int hist_blocks)
{
  const int bx = blockIdx.x;
  if (bx < conv_blocks) {
    long t = (long)bx * 256 + threadIdx.x;
    long b8 = t * 8;
    if (b8 + 8 <= total_nf) {
      const float* p = nf + b8;
      *(bf16x8*)(nf16 + b8) = pack8(*(const float4*)p, *(const float4*)(p + 4));
    }
  } else if (bx == conv_blocks) {
    int t = threadIdx.x;
#pragma unroll
    for (int j = 0; j < 8; ++j) {
      int id = t * 8 + j;
      int w = id >> 10, kc = (id >> 8) & 3, nc = (id >> 6) & 3, lane = id & 63;
      int r = lane & 15, g = lane >> 4;
      const float* W = w ? Wa : Wm;
      const float* p = W + (nc * 16 + r) * 128 + kc * 32 + g * 8;
      *(bf16x8*)(wpack + (long)id * 8) = pack8(*(const float4*)p, *(const float4*)(p + 4));
    }
  } else {
    const int hb = bx - conv_blocks - 1;
    int i4 = hb * 256 + threadIdx.x;
    const int stride = hist_blocks * 256;
    const int E4 = E >> 2;
    for (; i4 < E4; i4 += stride) {
      const int4 d = ((const int4*)dst)[i4];
      atomicAdd(&hist[d.x], 1);
      atomicAdd(&hist[d.y], 1);
      atomicAdd(&hist[d.z], 1);
      atomicAdd(&hist[d.w], 1);
    }
    if (hb == 0) {
      int i = (E & ~3) + (int)threadIdx.x;
      if (i < E) atomicAdd(&hist[dst[i]], 1);
    }
  }
}

// ---- CSR scan ----
__global__ __launch_bounds__(256) void scan1_k(const int* __restrict__ hist,
                                               int* __restrict__ off,
                                               int* __restrict__ parts, int N) {
  __shared__ int sh[256];
  int tid = threadIdx.x;
  int base = blockIdx.x * 1024 + tid * 4;
  int v[4], ts = 0;
#pragma unroll
  for (int j = 0; j < 4; ++j) {
    int idx = base + j;
    v[j] = (idx < N) ? hist[idx] : 0;
    ts += v[j];
  }
  sh[tid] = ts;
  __syncthreads();
  for (int o = 1; o < 256; o <<= 1) {
    int y = (tid >= o) ? sh[tid - o] : 0;
    __syncthreads();
    sh[tid] += y;
    __syncthreads();
  }
  int run = sh[tid] - ts;
#pragma unroll
  for (int j = 0; j < 4; ++j) {
    int idx = base + j;
    if (idx < N) off[idx] = run;
    run += v[j];
  }
  if (tid == 255) parts[blockIdx.x] = sh[255];
}

__global__ void scan2_k(int* __restrict__ parts, int* __restrict__ off,
                        int nparts, int N, int E) {
  int lane = threadIdx.x & 63;
  int i0 = 2 * lane, i1 = 2 * lane + 1;
  int p0 = (i0 < nparts) ? parts[i0] : 0;
  int p1 = (i1 < nparts) ? parts[i1] : 0;
  int s = p0 + p1;
  int x = s;
  for (int o = 1; o < 64; o <<= 1) {
    int y = __shfl_up(x, o);
    if (lane >= o) x += y;
  }
  int ex = x - s;
  if (i0 < nparts) parts[i0] = ex;
  if (i1 < nparts) parts[i1] = ex + p0;
  if (lane == 0) off[N] = E;
}

__global__ __launch_bounds__(256) void scan3_k(int* __restrict__ off,
                                               int* __restrict__ woff,
                                               const int* __restrict__ parts, int N) {
  int p = parts[blockIdx.x];
  int base = blockIdx.x * 1024 + threadIdx.x;
#pragma unroll
  for (int j = 0; j < 4; ++j) {
    int idx = base + j * 256;
    if (idx < N) {
      int v = off[idx] + p;
      off[idx] = v;
      woff[idx] = v;
    }
  }
}

// ---- bin: one 8B scattered store per edge (eid, src) ----
__global__ __launch_bounds__(256) void bin_k(
    const int* __restrict__ src, const int* __restrict__ dst,
    int* __restrict__ woff, int2* __restrict__ packed, int E) {
  int i4 = blockIdx.x * blockDim.x + threadIdx.x;
  const int stride = gridDim.x * blockDim.x;
  const int E4 = E >> 2;
  for (; i4 < E4; i4 += stride) {
    const int4 d = ((const int4*)dst)[i4];
    const int4 s = ((const int4*)src)[i4];
    const int e0 = i4 * 4;
    int p;
    p = atomicAdd(&woff[d.x], 1); packed[p] = make_int2(e0 + 0, s.x);
    p = atomicAdd(&woff[d.y], 1); packed[p] = make_int2(e0 + 1, s.y);
    p = atomicAdd(&woff[d.z], 1); packed[p] = make_int2(e0 + 2, s.z);
    p = atomicAdd(&woff[d.w], 1); packed[p] = make_int2(e0 + 3, s.w);
  }
  if (blockIdx.x == 0) {
    int i = (E & ~3) + (int)threadIdx.x;
    if (i < E) {
      int p = atomicAdd(&woff[dst[i]], 1);
      packed[p] = make_int2(i, src[i]);
    }
  }
}

// ---- gather-reduce: wave per node, float4 lanes, 4 edges per iteration ----
__global__ __launch_bounds__(256) void reduce_k(
    const float* __restrict__ nf, const float* __restrict__ ef,
    const int* __restrict__ off, const int2* __restrict__ packed,
    short* __restrict__ ssum16, int N)
{
  const int wave = (blockIdx.x * blockDim.x + threadIdx.x) >> 6;
  const int lane = threadIdx.x & 63;
  if (wave >= N) return;
  const int g = lane >> 4;        // edge slot 0..3
  const int s = lane & 15;        // dim quad 0..15
  const int beg = off[wave], end = off[wave + 1];

  float4 anf = make_float4(0.f, 0.f, 0.f, 0.f);
  float4 aef = make_float4(0.f, 0.f, 0.f, 0.f);

  int i = beg;
  const int nfull = (end - beg) & ~3;
  for (; i < beg + nfull; i += 4) {
    const int2 pk = packed[i + g];
    const float4 x = *(const float4*)(nf + (size_t)pk.y * 64 + s * 4);
    const float4 y = *(const float4*)(ef + (size_t)pk.x * 64 + s * 4);
    anf.x += x.x; anf.y += x.y; anf.z += x.z; anf.w += x.w;
    aef.x += y.x; aef.y += y.y; aef.z += y.z; aef.w += y.w;
  }
  const int rem = end - i;
  if (g < rem) {
    const int2 pk = packed[i + g];
    const float4 x = *(const float4*)(nf + (size_t)pk.y * 64 + s * 4);
    const float4 y = *(const float4*)(ef + (size_t)pk.x * 64 + s * 4);
    anf.x += x.x; anf.y += x.y; anf.z += x.z; anf.w += x.w;
    aef.x += y.x; aef.y += y.y; aef.z += y.z; aef.w += y.w;
  }

  // combine the 4 edge slots (lanes ^16, ^32)
#pragma unroll
  for (int m = 16; m <= 32; m <<= 1) {
    anf.x += __shfl_xor(anf.x, m); anf.y += __shfl_xor(anf.y, m);
    anf.z += __shfl_xor(anf.z, m); anf.w += __shfl_xor(anf.w, m);
    aef.x += __shfl_xor(aef.x, m); aef.y += __shfl_xor(aef.y, m);
    aef.z += __shfl_xor(aef.z, m); aef.w += __shfl_xor(aef.w, m);
  }

  short* row = ssum16 + (size_t)wave * 128;
  if (g == 0) {
    *(bf16x4*)(row + s * 4) = pack4(anf);
  } else if (g == 1) {
    *(bf16x4*)(row + 64 + s * 4) = pack4(aef);
  }
}

// ---- fused node GEMMs (bf16 inputs, pre-packed weights) ----
// mfma_f32_16x16x32_bf16 maps: A[i][k]: lane=(k/8)*16+i, elem=k%8 ;
// B[k][j]: lane=(k/8)*16+j, elem=k%8 ; D[i][j]: lane=(i/4)*16+j, reg=i%4.
__global__ __launch_bounds__(256) void node_apply(
    const short* __restrict__ nf16, const short* __restrict__ ssum16,
    const int* __restrict__ off, const short* __restrict__ wpack,
    const float* __restrict__ b_msg, const float* __restrict__ b_apply,
    float* __restrict__ out, int ntiles)
{
  __shared__ float hn[4][16 * 68];
  const int wid = threadIdx.x >> 6;
  const int lane = threadIdx.x & 63;
  const int r = lane & 15;
  const int g = lane >> 4;
  const int tile = blockIdx.x * 4 + wid;
  if (tile >= ntiles) return;
  const int n0 = tile * 16;

  bf16x8 wm[4][4], wa[4][4];
#pragma unroll
  for (int kc = 0; kc < 4; ++kc)
#pragma unroll
    for (int nc = 0; nc < 4; ++nc) {
      wm[kc][nc] = *(const bf16x8*)(wpack + ((long)((0 * 4 + kc) * 4 + nc) * 64 + lane) * 8);
      wa[kc][nc] = *(const bf16x8*)(wpack + ((long)((1 * 4 + kc) * 4 + nc) * 64 + lane) * 8);
    }

  // GEMM1: msum = ssum(16x128) @ W_msg^T
  f32x4 acc[4] = {};
#pragma unroll
  for (int kc = 0; kc < 4; ++kc) {
    const bf16x8 af = *(const bf16x8*)(ssum16 + (size_t)(n0 + r) * 128 + kc * 32 + g * 8);
#pragma unroll
    for (int nc = 0; nc < 4; ++nc)
      acc[nc] = __builtin_amdgcn_mfma_f32_16x16x32_bf16(af, wm[kc][nc], acc[nc], 0, 0, 0);
  }

  // h_neigh = cnt>0 ? msum/cnt + b_msg : 0  -> LDS (same wave, no barrier)
  float cn[4];
#pragma unroll
  for (int q = 0; q < 4; ++q) {
    int n = n0 + g * 4 + q;
    cn[q] = (float)(off[n + 1] - off[n]);
  }
#pragma unroll
  for (int nc = 0; nc < 4; ++nc) {
    const float bm = b_msg[nc * 16 + r];
#pragma unroll
    for (int q = 0; q < 4; ++q) {
      const float v = cn[q] > 0.f ? acc[nc][q] / cn[q] + bm : 0.f;
      hn[wid][(g * 4 + q) * 68 + nc * 16 + r] = v;
    }
  }

  // GEMM2: out = [nfeats ‖ h_neigh](16x128) @ W_apply^T
  f32x4 acc2[4] = {};
#pragma unroll
  for (int kc = 0; kc < 2; ++kc) {
    const bf16x8 af = *(const bf16x8*)(nf16 + (size_t)(n0 + r) * 64 + kc * 32 + g * 8);
#pragma unroll
    for (int nc = 0; nc < 4; ++nc)
      acc2[nc] = __builtin_amdgcn_mfma_f32_16x16x32_bf16(af, wa[kc][nc], acc2[nc], 0, 0, 0);
  }
#pragma unroll
  for (int kc = 2; kc < 4; ++kc) {
    const float* p = &hn[wid][r * 68 + (kc - 2) * 32 + g * 8];
    const bf16x8 af = pack8(*(const float4*)p, *(const float4*)(p + 4));
#pragma unroll
    for (int nc = 0; nc < 4; ++nc)
      acc2[nc] = __builtin_amdgcn_mfma_f32_16x16x32_bf16(af, wa[kc][nc], acc2[nc], 0, 0, 0);
  }

#pragma unroll
  for (int nc = 0; nc < 4; ++nc) {
    const float ba = b_apply[nc * 16 + r];
#pragma unroll
    for (int q = 0; q < 4; ++q) {
      float v = acc2[nc][q] + ba;
      v = v > 0.f ? v : 0.f;
      out[(size_t)(n0 + g * 4 + q) * 64 + nc * 16 + r] = v;
    }
  }
}

extern "C" void kernel_launch(void* const* d_in, const int* in_sizes, int n_in,
                              void* d_out, int out_size, void* d_ws, size_t ws_size,
                              hipStream_t stream) {
  const float* nfeats  = (const float*)d_in[0];
  const float* efeats  = (const float*)d_in[1];
  const int*   src     = (const int*)d_in[2];
  const int*   dst     = (const int*)d_in[3];
  const float* b_msg   = (const float*)d_in[5];
  const float* W_msg   = (const float*)d_in[4];
  const float* W_apply = (const float*)d_in[6];
  const float* b_apply = (const float*)d_in[7];
  float* out = (float*)d_out;

  const int N = in_sizes[0] / 64;
  const int E = in_sizes[2];
  const int nparts = (N + 1023) / 1024;

  auto alignup = [](size_t x) { return (x + 127) & ~(size_t)127; };
  char* ws = (char*)d_ws;
  size_t o = 0;
  int*  hist   = (int*)(ws + o);  o = alignup(o + (size_t)N * 4);
  int*  off    = (int*)(ws + o);  o = alignup(o + (size_t)(N + 1) * 4);
  int*  woff   = (int*)(ws + o);  o = alignup(o + (size_t)N * 4);
  int*  parts  = (int*)(ws + o);  o = alignup(o + (size_t)nparts * 4);
  int2* packed = (int2*)(ws + o); o = alignup(o + (size_t)E * 8);
  short* ssum16 = (short*)(ws + o); o = alignup(o + (size_t)N * 128 * 2);
  short* nf16   = (short*)(ws + o); o = alignup(o + (size_t)N * 64 * 2);
  short* wpack  = (short*)(ws + o); o = alignup(o + (size_t)2048 * 8 * 2);

  hipMemsetAsync(hist, 0, (size_t)N * 4, stream);

  const long total_nf = (long)N * 64;
  const int conv_blocks = (int)((total_nf / 8 + 255) / 256);
  const int hist_blocks = 1024;
  prep_hist_k<<<conv_blocks + 1 + hist_blocks, 256, 0, stream>>>(
      nfeats, W_msg, W_apply, nf16, wpack, dst, hist,
      conv_blocks, total_nf, E, hist_blocks);
  scan1_k<<<nparts, 256, 0, stream>>>(hist, off, parts, N);
  scan2_k<<<1, 64, 0, stream>>>(parts, off, nparts, N, E);
  scan3_k<<<nparts, 256, 0, stream>>>(off, woff, parts, N);
  bin_k<<<1024, 256, 0, stream>>>(src, dst, woff, packed, E);
  reduce_k<<<(N + 3) / 4, 256, 0, stream>>>(nfeats, efeats, off, packed, ssum16, N);

  const int ntiles = (N + 15) / 16;
  node_apply<<<(ntiles + 3) / 4, 256, 0, stream>>>(nf16, ssum16, off, wpack,
                                                   b_msg, b_apply, out, ntiles);
}